// Round 8
// baseline (2441.032 us; speedup 1.0000x reference)
//
#include <hip/hip_runtime.h>
#include <hip/hip_bf16.h>
#include <cstdint>
#include <cstddef>

// ODE: dy/dt = tanh(y@W1+b1)@W2+b2.
// RK4: 7 steps h=0.2 + 1 step h=0.15 -> 32 flow evals; interior outputs via
// cubic Hermite dense output (f = adjacent steps' k1; last step uses its k4).
// Multi-kernel, 2 dispatches per eval:
//   g1_k : Abuf = tanh(state @ W1 + b1)        512 blocks x 128 thr, K=1024
//   g2c_k: F = Abuf @ W2 (FULL K=4096) + b2, with RK4 combine + Hermite
//          fused into the epilogue               128 blocks x 128 thr
// GEMM core: bf16 MFMA 16x16x32, 64x64 tiles, 2 waves, 2-ring LDS dbuf,
// XOR bank swizzle on global src + ds_read, explicit XCD-ownership mapping.

#define GAS __attribute__((address_space(1)))
#define LAS __attribute__((address_space(3)))

typedef __bf16 bf16x8 __attribute__((ext_vector_type(8)));
typedef float  f32x4  __attribute__((ext_vector_type(4)));
typedef unsigned short u16;

struct P {
  const float *x, *W1, *b1, *W2, *b2;
  float* out;
  u16 *W1t, *W2t, *ybf, *ytbf, *Abuf;
  float *y, *k1a, *k1b, *kb2, *kb3, *kb4;
};

__device__ __forceinline__ u16 f2bf(float f) {
  __hip_bfloat16 h = __float2bfloat16(f);
  return __builtin_bit_cast(u16, h);
}

// ---------------- transpose + convert: W[K][N] fp32 -> Wt[N][K] bf16 ----------------
__global__ __launch_bounds__(256) void transpose_bf16(
    const float* __restrict__ W, u16* __restrict__ Wt, int K, int N) {
  __shared__ u16 tile[32][33];
  int kb = blockIdx.x << 5, nb = blockIdx.y << 5;
  int tx = threadIdx.x & 31, ty = threadIdx.x >> 5;  // 32x8
  #pragma unroll
  for (int i = 0; i < 32; i += 8)
    tile[ty + i][tx] = f2bf(W[(size_t)(kb + ty + i) * N + nb + tx]);
  __syncthreads();
  #pragma unroll
  for (int i = 0; i < 32; i += 8)
    Wt[(size_t)(nb + ty + i) * K + kb + tx] = tile[tx][ty + i];
}

// ---------------- init: y=x, ybf=bf16(x), out[0]=x ----------------
__global__ __launch_bounds__(256) void init_state(
    const float* __restrict__ x, float* __restrict__ y,
    u16* __restrict__ ybf, float* __restrict__ out0) {
  int i = blockIdx.x * 256 + threadIdx.x;
  float4 v = reinterpret_cast<const float4*>(x)[i];
  reinterpret_cast<float4*>(y)[i] = v;
  reinterpret_cast<float4*>(out0)[i] = v;
  reinterpret_cast<ushort4*>(ybf)[i] =
      make_ushort4(f2bf(v.x), f2bf(v.y), f2bf(v.z), f2bf(v.w));
}

// ---------------- staging: one 64x64 bf16 tile pair via global_load_lds ----------------
// LDS rows 128B; XOR swizzle slot ^= (row&7) applied on the GLOBAL source
// (LDS dest stays linear per gload_lds rules), matching the swizzled ds_read.
__device__ __forceinline__ void stage_tiles(
    const u16* __restrict__ A, const u16* __restrict__ Bt,
    char* AsB, char* BsB, int m0, int n0, int kt, int K, int tid) {
  #pragma unroll
  for (int i = 0; i < 4; ++i) {
    int j = i * 128 + tid;
    int row = j >> 3, slot = j & 7, kc = slot ^ (row & 7);
    __builtin_amdgcn_global_load_lds(
        (const GAS void*)(A + (size_t)(m0 + row) * K + kt + kc * 8),
        (LAS void*)(AsB + j * 16), 16, 0, 0);
  }
  #pragma unroll
  for (int i = 0; i < 4; ++i) {
    int j = i * 128 + tid;
    int row = j >> 3, slot = j & 7, kc = slot ^ (row & 7);
    __builtin_amdgcn_global_load_lds(
        (const GAS void*)(Bt + (size_t)(n0 + row) * K + kt + kc * 8),
        (LAS void*)(BsB + j * 16), 16, 0, 0);
  }
}

// ---------------- GEMM main loop: acc(64x64) over K-range, 2-ring dbuf ----------------
// 2 waves (row halves), wave tile 32x64, mfma 16x16x32.
__device__ __forceinline__ void gemm_loop(
    const u16* __restrict__ A, const u16* __restrict__ Bt,
    int K, int m0, int n0, int nt, f32x4 acc[2][4],
    u16 (*As)[4096], u16 (*Bs)[4096], int tid) {
  const int lane = tid & 63;
  const int wid  = tid >> 6;
  const int lrow = lane & 15;
  const int kgrp = lane >> 4;

  stage_tiles(A, Bt, (char*)As[0], (char*)Bs[0], m0, n0, 0, K, tid);
  __syncthreads();
  int cur = 0;
  for (int t = 0; t < nt; ++t) {
    if (t + 1 < nt)
      stage_tiles(A, Bt, (char*)As[cur ^ 1], (char*)Bs[cur ^ 1],
                  m0, n0, (t + 1) * 64, K, tid);
    const char* AsB = (const char*)As[cur];
    const char* BsB = (const char*)Bs[cur];
    #pragma unroll
    for (int ks = 0; ks < 2; ++ks) {
      bf16x8 af[2], bfr[4];
      #pragma unroll
      for (int mi = 0; mi < 2; ++mi) {
        int row = wid * 32 + mi * 16 + lrow;
        int slot = (ks * 4 + kgrp) ^ (row & 7);
        af[mi] = *(const bf16x8*)(AsB + row * 128 + slot * 16);
      }
      #pragma unroll
      for (int ni = 0; ni < 4; ++ni) {
        int row = ni * 16 + lrow;
        int slot = (ks * 4 + kgrp) ^ (row & 7);
        bfr[ni] = *(const bf16x8*)(BsB + row * 128 + slot * 16);
      }
      #pragma unroll
      for (int mi = 0; mi < 2; ++mi)
        #pragma unroll
        for (int ni = 0; ni < 4; ++ni)
          acc[mi][ni] = __builtin_amdgcn_mfma_f32_16x16x32_bf16(
              af[mi], bfr[ni], acc[mi][ni], 0, 0, 0);
    }
    __syncthreads();
    cur ^= 1;
  }
}

// ---------------- GEMM1: Abuf = tanh(state @ W1t^T + b1) ----------------
// grid 512: xcd=bid&7 owns n-slice [xcd*8 .. xcd*8+8) of 64 n-tiles.
__global__ __launch_bounds__(128) void g1_k(P p, const u16* __restrict__ st) {
  __shared__ __attribute__((aligned(16))) u16 As[2][4096];
  __shared__ __attribute__((aligned(16))) u16 Bs[2][4096];
  const int tid = threadIdx.x, bid = blockIdx.x;
  const int xcd = bid & 7, j = bid >> 3;
  const int ntile = xcd * 8 + (j & 7), mtile = j >> 3;
  const int m0 = mtile * 64, n0 = ntile * 64;

  f32x4 acc[2][4];
  #pragma unroll
  for (int mi = 0; mi < 2; ++mi)
    #pragma unroll
    for (int ni = 0; ni < 4; ++ni) acc[mi][ni] = (f32x4){0.f, 0.f, 0.f, 0.f};

  gemm_loop(st, p.W1t, 1024, m0, n0, 16, acc, As, Bs, tid);

  const int lane = tid & 63, wid = tid >> 6;
  const int lrow = lane & 15, kgrp = lane >> 4;
  // C/D layout: col = lane&15, row = (lane>>4)*4 + reg (m89)
  #pragma unroll
  for (int mi = 0; mi < 2; ++mi) {
    #pragma unroll
    for (int ni = 0; ni < 4; ++ni) {
      int gcol = n0 + ni * 16 + lrow;
      float bb = p.b1[gcol];
      #pragma unroll
      for (int r = 0; r < 4; ++r) {
        int grow = m0 + wid * 32 + mi * 16 + kgrp * 4 + r;
        p.Abuf[(size_t)grow * 4096 + gcol] = f2bf(tanhf(acc[mi][ni][r] + bb));
      }
    }
  }
}

// ---------------- GEMM2 (FULL K=4096) + fused RK4 combine + Hermite ----------------
// grid 128: xcd=bid&7 owns n-slice [xcd*2 .. xcd*2+2) of 16 n-tiles.
__global__ __launch_bounds__(128) void g2c_k(P p, int n, int e) {
  __shared__ __attribute__((aligned(16))) u16 As[2][4096];
  __shared__ __attribute__((aligned(16))) u16 Bs[2][4096];
  const int tid = threadIdx.x, bid = blockIdx.x;
  const int xcd = bid & 7, j = bid >> 3;
  const int ntile = xcd * 2 + (j & 1), mtile = j >> 1;
  const int m0 = mtile * 64, n0 = ntile * 64;
  const int MN = 524288;

  f32x4 acc[2][4];
  #pragma unroll
  for (int mi = 0; mi < 2; ++mi)
    #pragma unroll
    for (int ni = 0; ni < 4; ++ni) acc[mi][ni] = (f32x4){0.f, 0.f, 0.f, 0.f};

  gemm_loop(p.Abuf, p.W2t, 4096, m0, n0, 64, acc, As, Bs, tid);

  const float h = (n < 7) ? 0.2f : 0.15f;
  const float h6 = h / 6.f;
  const float coef = (e == 3) ? h : h * 0.5f;
  float* k1buf = (n & 1) ? p.k1b : p.k1a;
  const float* k1prev = (n & 1) ? p.k1a : p.k1b;
  float* kbuf = (e == 1) ? k1buf : (e == 2 ? p.kb2 : p.kb3);
  // Hermite coefs (theta=1/4,1/2,3/4 at h=0.2): {y0, f0*h, y1, f1*h}
  const float4 hc0 = {0.84375f, 0.028125f, 0.15625f, -0.009375f};
  const float4 hc1 = {0.5f,     0.025f,    0.5f,     -0.025f};
  const float4 hc2 = {0.15625f, 0.009375f, 0.84375f, -0.028125f};
  const int outIdx = (n < 7) ? 4 * (n + 1) : 31;

  const int lane = tid & 63, wid = tid >> 6;
  const int lrow = lane & 15, kgrp = lane >> 4;
  #pragma unroll
  for (int mi = 0; mi < 2; ++mi) {
    #pragma unroll
    for (int ni = 0; ni < 4; ++ni) {
      int gcol = n0 + ni * 16 + lrow;
      float bb = p.b2[gcol];
      #pragma unroll
      for (int r = 0; r < 4; ++r) {
        int grow = m0 + wid * 32 + mi * 16 + kgrp * 4 + r;
        size_t gi = (size_t)grow * 1024 + gcol;
        float F = acc[mi][ni][r] + bb;
        float yv = p.y[gi];
        if (e < 4) {
          kbuf[gi] = F;
          float nv = yv + coef * F;
          p.ytbf[gi] = f2bf(nv);
          if (e == 1 && n >= 1) {  // Hermite dense output for interval n-1
            float yA = p.out[(size_t)(4 * n - 4) * MN + gi];
            float yB = p.out[(size_t)(4 * n) * MN + gi];
            float f0 = k1prev[gi];
            p.out[(size_t)(4 * n - 3) * MN + gi] =
                hc0.x * yA + hc0.y * f0 + hc0.z * yB + hc0.w * F;
            p.out[(size_t)(4 * n - 2) * MN + gi] =
                hc1.x * yA + hc1.y * f0 + hc1.z * yB + hc1.w * F;
            p.out[(size_t)(4 * n - 1) * MN + gi] =
                hc2.x * yA + hc2.y * f0 + hc2.z * yB + hc2.w * F;
          }
        } else {
          if (n == 7) p.kb4[gi] = F;
          float nv = yv + h6 * (k1buf[gi] + 2.f * p.kb2[gi] +
                                2.f * p.kb3[gi] + F);
          p.y[gi] = nv;
          p.out[(size_t)outIdx * MN + gi] = nv;
          p.ybf[gi] = f2bf(nv);
        }
      }
    }
  }
}

// ---------------- tail Hermite: [out28, out31], h=0.15, theta=1/3,2/3 ----------------
__global__ __launch_bounds__(256) void tail_k(P p) {
  const int q = 131072;  // float4s per [512x1024]
  const float4 tc0 = {0.7407407f, 0.0222222f, 0.2592593f, -0.0111111f};
  const float4 tc1 = {0.2592593f, 0.0111111f, 0.7407407f, -0.0222222f};
  int i = blockIdx.x * 256 + threadIdx.x;
  float4* o4 = (float4*)p.out;
  float4 A_ = o4[(size_t)28 * q + i];
  float4 B_ = o4[(size_t)31 * q + i];
  float4 C_ = ((const float4*)p.k1b)[i];  // k1 of step 7
  float4 D_ = ((const float4*)p.kb4)[i];  // k4 of step 7
  float4 o;
  o.x = tc0.x * A_.x + tc0.y * C_.x + tc0.z * B_.x + tc0.w * D_.x;
  o.y = tc0.x * A_.y + tc0.y * C_.y + tc0.z * B_.y + tc0.w * D_.y;
  o.z = tc0.x * A_.z + tc0.y * C_.z + tc0.z * B_.z + tc0.w * D_.z;
  o.w = tc0.x * A_.w + tc0.y * C_.w + tc0.z * B_.w + tc0.w * D_.w;
  o4[(size_t)29 * q + i] = o;
  o.x = tc1.x * A_.x + tc1.y * C_.x + tc1.z * B_.x + tc1.w * D_.x;
  o.y = tc1.x * A_.y + tc1.y * C_.y + tc1.z * B_.y + tc1.w * D_.y;
  o.z = tc1.x * A_.z + tc1.y * C_.z + tc1.z * B_.z + tc1.w * D_.z;
  o.w = tc1.x * A_.w + tc1.y * C_.w + tc1.z * B_.w + tc1.w * D_.w;
  o4[(size_t)30 * q + i] = o;
}

extern "C" void kernel_launch(void* const* d_in, const int* in_sizes, int n_in,
                              void* d_out, int out_size, void* d_ws, size_t ws_size,
                              hipStream_t stream) {
  P p;
  p.x  = (const float*)d_in[0];
  p.W1 = (const float*)d_in[1];
  p.b1 = (const float*)d_in[2];
  p.W2 = (const float*)d_in[3];
  p.b2 = (const float*)d_in[4];
  p.out = (float*)d_out;

  const int Dq = 1024, Hq = 4096;
  const int MN = 512 * 1024;
  char* ws = (char*)d_ws;
  size_t off = 0;
  p.W1t  = (u16*)(ws + off);   off += (size_t)Hq * Dq * 2;   // 8 MB
  p.W2t  = (u16*)(ws + off);   off += (size_t)Dq * Hq * 2;   // 8 MB
  p.y    = (float*)(ws + off); off += (size_t)MN * 4;        // 2 MB
  p.ybf  = (u16*)(ws + off);   off += (size_t)MN * 2;        // 1 MB
  p.ytbf = (u16*)(ws + off);   off += (size_t)MN * 2;        // 1 MB
  p.Abuf = (u16*)(ws + off);   off += (size_t)512 * Hq * 2;  // 4 MB
  p.k1a  = (float*)(ws + off); off += (size_t)MN * 4;
  p.k1b  = (float*)(ws + off); off += (size_t)MN * 4;
  p.kb2  = (float*)(ws + off); off += (size_t)MN * 4;
  p.kb3  = (float*)(ws + off); off += (size_t)MN * 4;
  p.kb4  = (float*)(ws + off); off += (size_t)MN * 4;
  if (ws_size < off) return;

  transpose_bf16<<<dim3(Dq / 32, Hq / 32), 256, 0, stream>>>(p.W1, p.W1t, Dq, Hq);
  transpose_bf16<<<dim3(Hq / 32, Dq / 32), 256, 0, stream>>>(p.W2, p.W2t, Hq, Dq);
  init_state<<<MN / 4 / 256, 256, 0, stream>>>(p.x, p.y, p.ybf, p.out);

  // 8 steps: n=0..6 h=0.2 (-> out[4(n+1)]), n=7 h=0.15 (-> out[31])
  for (int n = 0; n < 8; ++n) {
    for (int e = 1; e <= 4; ++e) {
      g1_k<<<512, 128, 0, stream>>>(p, (e == 1) ? p.ybf : p.ytbf);
      g2c_k<<<128, 128, 0, stream>>>(p, n, e);
    }
  }
  tail_k<<<512, 256, 0, stream>>>(p);
}

// Round 9
// 1151.807 us; speedup vs baseline: 2.1193x; 2.1193x over previous
//
#include <hip/hip_runtime.h>
#include <hip/hip_bf16.h>
#include <cstdint>
#include <cstddef>

// ODE: dy/dt = tanh(y@W1+b1)@W2+b2.
// RK4: 7 steps h=0.2 + 1 step h=0.15 -> 32 flow evals; interior outputs via
// cubic Hermite dense output. 2 dispatches per eval:
//  g1_k : 1024 blocks x 128 thr. Block tile 32x64, 2 waves = K-halves.
//  g2c_k:  512 blocks x 256 thr. Block tile 32x32, 4 waves = K-quarters,
//          full K=4096 per block -> RK4 combine + Hermite fused in epilogue.
// Each WAVE is a private GEMM worker: own LDS ring (ring-3, BK=32),
// depth-2 prefetch, per-wave counted s_waitcnt vmcnt, NO barriers in K-loop.
// 2 waves/SIMD resident -> latency hidden by cross-wave overlap + pipeline.

#define GAS __attribute__((address_space(1)))
#define LAS __attribute__((address_space(3)))

typedef __bf16 bf16x8 __attribute__((ext_vector_type(8)));
typedef float  f32x4  __attribute__((ext_vector_type(4)));
typedef unsigned short u16;

struct P {
  const float *x, *W1, *b1, *W2, *b2;
  float* out;
  u16 *W1t, *W2t, *ybf, *ytbf, *Abuf;
  float *y, *k1a, *k1b, *kb2, *kb3, *kb4;
};

__device__ __forceinline__ u16 f2bf(float f) {
  __hip_bfloat16 h = __float2bfloat16(f);
  return __builtin_bit_cast(u16, h);
}

// ---------------- transpose + convert: W[K][N] fp32 -> Wt[N][K] bf16 ----------------
__global__ __launch_bounds__(256) void transpose_bf16(
    const float* __restrict__ W, u16* __restrict__ Wt, int K, int N) {
  __shared__ u16 tile[32][33];
  int kb = blockIdx.x << 5, nb = blockIdx.y << 5;
  int tx = threadIdx.x & 31, ty = threadIdx.x >> 5;  // 32x8
  #pragma unroll
  for (int i = 0; i < 32; i += 8)
    tile[ty + i][tx] = f2bf(W[(size_t)(kb + ty + i) * N + nb + tx]);
  __syncthreads();
  #pragma unroll
  for (int i = 0; i < 32; i += 8)
    Wt[(size_t)(nb + ty + i) * K + kb + tx] = tile[tx][ty + i];
}

// ---------------- init: y=x, ybf=bf16(x), out[0]=x ----------------
__global__ __launch_bounds__(256) void init_state(
    const float* __restrict__ x, float* __restrict__ y,
    u16* __restrict__ ybf, float* __restrict__ out0) {
  int i = blockIdx.x * 256 + threadIdx.x;
  float4 v = reinterpret_cast<const float4*>(x)[i];
  reinterpret_cast<float4*>(y)[i] = v;
  reinterpret_cast<float4*>(out0)[i] = v;
  reinterpret_cast<ushort4*>(ybf)[i] =
      make_ushort4(f2bf(v.x), f2bf(v.y), f2bf(v.z), f2bf(v.w));
}

// ---------------- per-wave staging of one R x 32 bf16 tile ----------------
// LDS rows are 64 B (BK=32). Swizzle: chunk (16B) slot ^= (row>>1)&3, applied
// on the GLOBAL source (LDS dest linear: wave-uniform base + lane*16),
// matching the swizzled ds_read below. CALLS = R/16 (R rows, 4 slots/row).
template<int CALLS>
__device__ __forceinline__ void stage_tile(
    const u16* __restrict__ src, int ldk, char* dst, int lane) {
  #pragma unroll
  for (int c = 0; c < CALLS; ++c) {
    int j0 = c * 64 + lane;
    int row = j0 >> 2, slot = j0 & 3;
    int kc = slot ^ ((row >> 1) & 3);
    __builtin_amdgcn_global_load_lds(
        (const GAS void*)(src + (size_t)row * ldk + kc * 8),
        (LAS void*)(dst + j0 * 16), 16, 0, 0);
  }
}

// swizzled ds_read of one bf16x8 fragment: row, k-group g (0..3)
__device__ __forceinline__ bf16x8 frag(const char* base, int row, int g) {
  return *(const bf16x8*)(base + row * 64 + ((g ^ ((row >> 1) & 3)) << 4));
}

// ---------------- GEMM1: Abuf = tanh(state @ W1t^T + b1) ----------------
// 1024 blocks x 128 thr. Block = one 32(M)x64(N) tile; wave wk = K-half.
// Per wave: nt=16 iters of BK=32; ring-3 (6 KB/ring); 6 loads+6 ds_read+8 MFMA.
__global__ __launch_bounds__(128) void g1_k(P p, const u16* __restrict__ st) {
  __shared__ __attribute__((aligned(16))) char L[36864];
  const int tid = threadIdx.x, lane = tid & 63, wk = tid >> 6;
  const int bid = blockIdx.x;
  const int xcd = bid & 7, j = bid >> 3;
  const int ntile = xcd * 8 + (j & 7), mtile = j >> 3;  // 64 x 16
  const int m0 = mtile * 32, n0 = ntile * 64;
  const int kb = wk * 512;
  char* wbase = L + wk * 18432;
  const int lrow = lane & 15, kgrp = lane >> 4;

  f32x4 acc[2][4];
  #pragma unroll
  for (int mi = 0; mi < 2; ++mi)
    #pragma unroll
    for (int ni = 0; ni < 4; ++ni) acc[mi][ni] = (f32x4){0.f, 0.f, 0.f, 0.f};

  const u16* Asrc = st + (size_t)m0 * 1024 + kb;
  const u16* Bsrc = p.W1t + (size_t)n0 * 1024 + kb;

#define G1_STAGE(t)                                                        \
  {                                                                        \
    char* rb = wbase + ((t) % 3) * 6144;                                   \
    stage_tile<2>(Asrc + (t) * 32, 1024, rb, lane);                        \
    stage_tile<4>(Bsrc + (t) * 32, 1024, rb + 2048, lane);                 \
  }

  G1_STAGE(0);
  G1_STAGE(1);
  for (int t = 0; t < 16; ++t) {
    if (t + 2 < 16) {
      G1_STAGE(t + 2);
      asm volatile("s_waitcnt vmcnt(12)" ::: "memory");
    } else if (t + 1 < 16) {
      asm volatile("s_waitcnt vmcnt(6)" ::: "memory");
    } else {
      asm volatile("s_waitcnt vmcnt(0)" ::: "memory");
    }
    __builtin_amdgcn_sched_barrier(0);
    const char* rb = wbase + (t % 3) * 6144;
    bf16x8 af[2], bf[4];
    #pragma unroll
    for (int mi = 0; mi < 2; ++mi) af[mi] = frag(rb, mi * 16 + lrow, kgrp);
    #pragma unroll
    for (int ni = 0; ni < 4; ++ni) bf[ni] = frag(rb + 2048, ni * 16 + lrow, kgrp);
    #pragma unroll
    for (int mi = 0; mi < 2; ++mi)
      #pragma unroll
      for (int ni = 0; ni < 4; ++ni)
        acc[mi][ni] = __builtin_amdgcn_mfma_f32_16x16x32_bf16(
            af[mi], bf[ni], acc[mi][ni], 0, 0, 0);
  }
#undef G1_STAGE

  // in-block K-reduction: wave1 -> LDS [32][65] fp32, wave0 adds + epilogue.
  __syncthreads();
  float* sc = (float*)L;
  if (wk == 1) {
    #pragma unroll
    for (int mi = 0; mi < 2; ++mi)
      #pragma unroll
      for (int ni = 0; ni < 4; ++ni)
        #pragma unroll
        for (int r = 0; r < 4; ++r) {
          int row = mi * 16 + kgrp * 4 + r, col = ni * 16 + lrow;
          sc[row * 65 + col] = acc[mi][ni][r];
        }
  }
  __syncthreads();
  if (wk == 0) {
    // C/D layout: col = lane&15, row = (lane>>4)*4 + reg (m89)
    #pragma unroll
    for (int mi = 0; mi < 2; ++mi)
      #pragma unroll
      for (int ni = 0; ni < 4; ++ni) {
        int gcol = n0 + ni * 16 + lrow;
        float bb = p.b1[gcol];
        #pragma unroll
        for (int r = 0; r < 4; ++r) {
          int row = mi * 16 + kgrp * 4 + r;
          float v = acc[mi][ni][r] + sc[row * 65 + ni * 16 + lrow] + bb;
          p.Abuf[(size_t)(m0 + row) * 4096 + gcol] = f2bf(tanhf(v));
        }
      }
  }
}

// ---------------- GEMM2 (full K=4096) + fused RK4 combine + Hermite ----------------
// 512 blocks x 256 thr. Block = one 32(M)x32(N) tile; wave wid = K-quarter.
// Per wave: nt=32 iters of BK=32; ring-3 (4 KB/ring); 4 loads+4 ds_read+4 MFMA.
__global__ __launch_bounds__(256) void g2c_k(P p, int n, int e) {
  __shared__ __attribute__((aligned(16))) char L[49152];
  const int tid = threadIdx.x, lane = tid & 63, wid = tid >> 6;
  const int bid = blockIdx.x;
  const int xcd = bid & 7, j = bid >> 3;
  const int ntile = xcd * 4 + (j & 3), mtile = j >> 2;  // 32 x 16
  const int m0 = mtile * 32, n0 = ntile * 32;
  const int kb = wid * 1024;
  char* wbase = L + wid * 12288;
  const int lrow = lane & 15, kgrp = lane >> 4;

  f32x4 acc[2][2];
  #pragma unroll
  for (int mi = 0; mi < 2; ++mi)
    #pragma unroll
    for (int ni = 0; ni < 2; ++ni) acc[mi][ni] = (f32x4){0.f, 0.f, 0.f, 0.f};

  const u16* Asrc = p.Abuf + (size_t)m0 * 4096 + kb;
  const u16* Bsrc = p.W2t + (size_t)n0 * 4096 + kb;

#define G2_STAGE(t)                                                        \
  {                                                                        \
    char* rb = wbase + ((t) % 3) * 4096;                                   \
    stage_tile<2>(Asrc + (t) * 32, 4096, rb, lane);                        \
    stage_tile<2>(Bsrc + (t) * 32, 4096, rb + 2048, lane);                 \
  }

  G2_STAGE(0);
  G2_STAGE(1);
  for (int t = 0; t < 32; ++t) {
    if (t + 2 < 32) {
      G2_STAGE(t + 2);
      asm volatile("s_waitcnt vmcnt(8)" ::: "memory");
    } else if (t + 1 < 32) {
      asm volatile("s_waitcnt vmcnt(4)" ::: "memory");
    } else {
      asm volatile("s_waitcnt vmcnt(0)" ::: "memory");
    }
    __builtin_amdgcn_sched_barrier(0);
    const char* rb = wbase + (t % 3) * 4096;
    bf16x8 af[2], bf[2];
    #pragma unroll
    for (int mi = 0; mi < 2; ++mi) af[mi] = frag(rb, mi * 16 + lrow, kgrp);
    #pragma unroll
    for (int ni = 0; ni < 2; ++ni) bf[ni] = frag(rb + 2048, ni * 16 + lrow, kgrp);
    #pragma unroll
    for (int mi = 0; mi < 2; ++mi)
      #pragma unroll
      for (int ni = 0; ni < 2; ++ni)
        acc[mi][ni] = __builtin_amdgcn_mfma_f32_16x16x32_bf16(
            af[mi], bf[ni], acc[mi][ni], 0, 0, 0);
  }
#undef G2_STAGE

  // in-block K-reduction: all 4 waves -> LDS [4][32][36] fp32
  __syncthreads();
  float* sc = (float*)L;
  #pragma unroll
  for (int mi = 0; mi < 2; ++mi)
    #pragma unroll
    for (int ni = 0; ni < 2; ++ni)
      #pragma unroll
      for (int r = 0; r < 4; ++r) {
        int row = mi * 16 + kgrp * 4 + r, col = ni * 16 + lrow;
        sc[wid * 1152 + row * 36 + col] = acc[mi][ni][r];
      }
  __syncthreads();

  // strip epilogue: each wave owns rows [wid*8, wid*8+8); lane -> (row, 4 cols)
  const int row = wid * 8 + (lane >> 3), c4 = (lane & 7) * 4;
  f32x4 Fv = (f32x4){0.f, 0.f, 0.f, 0.f};
  #pragma unroll
  for (int w = 0; w < 4; ++w)
    Fv += *(const f32x4*)(sc + w * 1152 + row * 36 + c4);

  const int rg = m0 + row, cg = n0 + c4;
  const int gi4 = rg * 256 + (cg >> 2);
  float4 bb = ((const float4*)p.b2)[cg >> 2];
  float4 F = make_float4(Fv[0] + bb.x, Fv[1] + bb.y, Fv[2] + bb.z, Fv[3] + bb.w);

  const float h = (n < 7) ? 0.2f : 0.15f;
  const float h6 = h / 6.f;
  const float coef = (e == 3) ? h : h * 0.5f;
  float* k1buf = (n & 1) ? p.k1b : p.k1a;
  const float* k1prev = (n & 1) ? p.k1a : p.k1b;
  // Hermite coefs (theta=1/4,1/2,3/4 at h=0.2): {y0, f0*h, y1, f1*h}
  const float4 hc0 = {0.84375f, 0.028125f, 0.15625f, -0.009375f};
  const float4 hc1 = {0.5f,     0.025f,    0.5f,     -0.025f};
  const float4 hc2 = {0.15625f, 0.009375f, 0.84375f, -0.028125f};
  const int q = 131072;  // float4s per [512x1024]

  float4 yv = ((const float4*)p.y)[gi4];
  if (e < 4) {
    float* kbuf = (e == 1) ? k1buf : (e == 2 ? p.kb2 : p.kb3);
    ((float4*)kbuf)[gi4] = F;
    float4 nv = make_float4(yv.x + coef * F.x, yv.y + coef * F.y,
                            yv.z + coef * F.z, yv.w + coef * F.w);
    ((ushort4*)p.ytbf)[gi4] =
        make_ushort4(f2bf(nv.x), f2bf(nv.y), f2bf(nv.z), f2bf(nv.w));
    if (e == 1 && n >= 1) {  // Hermite dense output for interval n-1, f1 = F
      float4* o4 = (float4*)p.out;
      float4 A_ = o4[(size_t)(4 * n - 4) * q + gi4];
      float4 B_ = o4[(size_t)(4 * n) * q + gi4];
      float4 C_ = ((const float4*)k1prev)[gi4];
      float4 o;
      o.x = hc0.x * A_.x + hc0.y * C_.x + hc0.z * B_.x + hc0.w * F.x;
      o.y = hc0.x * A_.y + hc0.y * C_.y + hc0.z * B_.y + hc0.w * F.y;
      o.z = hc0.x * A_.z + hc0.y * C_.z + hc0.z * B_.z + hc0.w * F.z;
      o.w = hc0.x * A_.w + hc0.y * C_.w + hc0.z * B_.w + hc0.w * F.w;
      o4[(size_t)(4 * n - 3) * q + gi4] = o;
      o.x = hc1.x * A_.x + hc1.y * C_.x + hc1.z * B_.x + hc1.w * F.x;
      o.y = hc1.x * A_.y + hc1.y * C_.y + hc1.z * B_.y + hc1.w * F.y;
      o.z = hc1.x * A_.z + hc1.y * C_.z + hc1.z * B_.z + hc1.w * F.z;
      o.w = hc1.x * A_.w + hc1.y * C_.w + hc1.z * B_.w + hc1.w * F.w;
      o4[(size_t)(4 * n - 2) * q + gi4] = o;
      o.x = hc2.x * A_.x + hc2.y * C_.x + hc2.z * B_.x + hc2.w * F.x;
      o.y = hc2.x * A_.y + hc2.y * C_.y + hc2.z * B_.y + hc2.w * F.y;
      o.z = hc2.x * A_.z + hc2.y * C_.z + hc2.z * B_.z + hc2.w * F.z;
      o.w = hc2.x * A_.w + hc2.y * C_.w + hc2.z * B_.w + hc2.w * F.w;
      o4[(size_t)(4 * n - 1) * q + gi4] = o;
    }
  } else {
    if (n == 7) ((float4*)p.kb4)[gi4] = F;
    float4 a = ((const float4*)k1buf)[gi4];
    float4 c = ((const float4*)p.kb2)[gi4];
    float4 d = ((const float4*)p.kb3)[gi4];
    float4 nv;
    nv.x = yv.x + h6 * (a.x + 2.f * c.x + 2.f * d.x + F.x);
    nv.y = yv.y + h6 * (a.y + 2.f * c.y + 2.f * d.y + F.y);
    nv.z = yv.z + h6 * (a.z + 2.f * c.z + 2.f * d.z + F.z);
    nv.w = yv.w + h6 * (a.w + 2.f * c.w + 2.f * d.w + F.w);
    ((float4*)p.y)[gi4] = nv;
    int outIdx = (n < 7) ? 4 * (n + 1) : 31;
    ((float4*)p.out)[(size_t)outIdx * q + gi4] = nv;
    ((ushort4*)p.ybf)[gi4] =
        make_ushort4(f2bf(nv.x), f2bf(nv.y), f2bf(nv.z), f2bf(nv.w));
  }
}

// ---------------- tail Hermite: [out28, out31], h=0.15, theta=1/3,2/3 ----------------
__global__ __launch_bounds__(256) void tail_k(P p) {
  const int q = 131072;
  const float4 tc0 = {0.7407407f, 0.0222222f, 0.2592593f, -0.0111111f};
  const float4 tc1 = {0.2592593f, 0.0111111f, 0.7407407f, -0.0222222f};
  int i = blockIdx.x * 256 + threadIdx.x;
  float4* o4 = (float4*)p.out;
  float4 A_ = o4[(size_t)28 * q + i];
  float4 B_ = o4[(size_t)31 * q + i];
  float4 C_ = ((const float4*)p.k1b)[i];  // k1 of step 7
  float4 D_ = ((const float4*)p.kb4)[i];  // k4 of step 7
  float4 o;
  o.x = tc0.x * A_.x + tc0.y * C_.x + tc0.z * B_.x + tc0.w * D_.x;
  o.y = tc0.x * A_.y + tc0.y * C_.y + tc0.z * B_.y + tc0.w * D_.y;
  o.z = tc0.x * A_.z + tc0.y * C_.z + tc0.z * B_.z + tc0.w * D_.z;
  o.w = tc0.x * A_.w + tc0.y * C_.w + tc0.z * B_.w + tc0.w * D_.w;
  o4[(size_t)29 * q + i] = o;
  o.x = tc1.x * A_.x + tc1.y * C_.x + tc1.z * B_.x + tc1.w * D_.x;
  o.y = tc1.x * A_.y + tc1.y * C_.y + tc1.z * B_.y + tc1.w * D_.y;
  o.z = tc1.x * A_.z + tc1.y * C_.z + tc1.z * B_.z + tc1.w * D_.z;
  o.w = tc1.x * A_.w + tc1.y * C_.w + tc1.z * B_.w + tc1.w * D_.w;
  o4[(size_t)30 * q + i] = o;
}

extern "C" void kernel_launch(void* const* d_in, const int* in_sizes, int n_in,
                              void* d_out, int out_size, void* d_ws, size_t ws_size,
                              hipStream_t stream) {
  P p;
  p.x  = (const float*)d_in[0];
  p.W1 = (const float*)d_in[1];
  p.b1 = (const float*)d_in[2];
  p.W2 = (const float*)d_in[3];
  p.b2 = (const float*)d_in[4];
  p.out = (float*)d_out;

  const int Dq = 1024, Hq = 4096;
  const int MN = 512 * 1024;
  char* ws = (char*)d_ws;
  size_t off = 0;
  p.W1t  = (u16*)(ws + off);   off += (size_t)Hq * Dq * 2;   // 8 MB
  p.W2t  = (u16*)(ws + off);   off += (size_t)Dq * Hq * 2;   // 8 MB
  p.y    = (float*)(ws + off); off += (size_t)MN * 4;        // 2 MB
  p.ybf  = (u16*)(ws + off);   off += (size_t)MN * 2;        // 1 MB
  p.ytbf = (u16*)(ws + off);   off += (size_t)MN * 2;        // 1 MB
  p.Abuf = (u16*)(ws + off);   off += (size_t)512 * Hq * 2;  // 4 MB
  p.k1a  = (float*)(ws + off); off += (size_t)MN * 4;
  p.k1b  = (float*)(ws + off); off += (size_t)MN * 4;
  p.kb2  = (float*)(ws + off); off += (size_t)MN * 4;
  p.kb3  = (float*)(ws + off); off += (size_t)MN * 4;
  p.kb4  = (float*)(ws + off); off += (size_t)MN * 4;
  if (ws_size < off) return;

  transpose_bf16<<<dim3(Dq / 32, Hq / 32), 256, 0, stream>>>(p.W1, p.W1t, Dq, Hq);
  transpose_bf16<<<dim3(Hq / 32, Dq / 32), 256, 0, stream>>>(p.W2, p.W2t, Hq, Dq);
  init_state<<<MN / 4 / 256, 256, 0, stream>>>(p.x, p.y, p.ybf, p.out);

  // 8 steps: n=0..6 h=0.2 (-> out[4(n+1)]), n=7 h=0.15 (-> out[31])
  for (int n = 0; n < 8; ++n) {
    for (int e = 1; e <= 4; ++e) {
      g1_k<<<1024, 128, 0, stream>>>(p, (e == 1) ? p.ybf : p.ytbf);
      g2c_k<<<512, 256, 0, stream>>>(p, n, e);
    }
  }
  tail_k<<<512, 256, 0, stream>>>(p);
}